// Round 26
// baseline (541.442 us; speedup 1.0000x reference)
//
#include <hip/hip_runtime.h>

#define HID 2048
#define NE_ 32
#define EW_ 2944
#define ORIG_ 2880
#define TOPK_ 4
#define MAXNNZ_ 256
#define BS_ 1024
#define NEWTOT (NE_*EW_)

typedef unsigned short u16;
typedef _Float16 h8  __attribute__((ext_vector_type(8)));
typedef float  f32x4 __attribute__((ext_vector_type(4)));
typedef float  fv4   __attribute__((ext_vector_type(4)));

__device__ __forceinline__ u16 f2h_bits(float f){
  union{ _Float16 h; u16 u; } c; c.h = (_Float16)f; return c.u;
}
__device__ __forceinline__ float f16q(float f){ return (float)(_Float16)f; }

__device__ __forceinline__ h8 cvt8(fv4 a, fv4 b){
  h8 r;
  r[0]=(_Float16)a[0]; r[1]=(_Float16)a[1]; r[2]=(_Float16)a[2]; r[3]=(_Float16)a[3];
  r[4]=(_Float16)b[0]; r[5]=(_Float16)b[1]; r[6]=(_Float16)b[2]; r[7]=(_Float16)b[3];
  return r;
}
// XOR-swizzled LDS index (halfword units), 64B rows, 16B chunks; write and
// read use the same per-row bijection.
__device__ __forceinline__ int ldsx(int row, int chunk){
  return row*32 + ((chunk ^ ((row>>1)&3))*8);
}

// LDS-visibility-only barrier: global loads into registers stay in flight.
__device__ __forceinline__ void barrier_lgkm(){
  asm volatile("s_waitcnt lgkmcnt(0)" ::: "memory");
  __builtin_amdgcn_s_barrier();
  __builtin_amdgcn_sched_barrier(0);
}

// expert ranking by count desc, tie -> lower index; returns k-th expert
__device__ __forceinline__ int rank_kth(const int* counts, int kth){
  int cnt[NE_]; bool used[NE_];
  for (int e=0;e<NE_;e++){ cnt[e]=counts[e]; used[e]=false; }
  int bi=0;
  for (int k=0;k<=kth;k++){
    int best=-1; bi=0;
    for (int e=0;e<NE_;e++) if(!used[e] && cnt[e]>best){best=cnt[e];bi=e;}
    used[bi]=true;
  }
  return bi;
}

// ------- gating (f32 in, f16-quantized logits, top4) + xh emission ----------
__global__ __launch_bounds__(256) void k_gate(const float* __restrict__ x,
                                              const float* __restrict__ gw,
                                              float* __restrict__ rw,
                                              float* __restrict__ rwf,
                                              int* __restrict__ counts,
                                              u16* __restrict__ xh)
{
  __shared__ float slog[4][NE_];
  const int tid = threadIdx.x, wid = tid>>6, lane = tid&63;
  const int n = blockIdx.x*4 + wid;
  const float* xr = x + (size_t)n*HID + lane*32;
  float xf[32];
  #pragma unroll
  for (int i=0;i<8;i++){
    fv4 v = *(const fv4*)(xr + i*4);
    #pragma unroll
    for (int j=0;j<4;j++) xf[i*4+j] = v[j];
  }
  #pragma unroll
  for (int c=0;c<4;c++){
    h8 hv;
    #pragma unroll
    for (int j=0;j<8;j++) hv[j] = (_Float16)xf[c*8+j];
    *(h8*)(xh + (size_t)n*HID + lane*32 + c*8) = hv;
  }
  for (int e=0;e<NE_;e++){
    const float* gr = gw + (size_t)e*HID + lane*32;
    float p = 0.f;
    #pragma unroll
    for (int i=0;i<8;i++){
      fv4 v = *(const fv4*)(gr + i*4);
      #pragma unroll
      for (int j=0;j<4;j++) p += xf[i*4+j]*v[j];
    }
    #pragma unroll
    for (int s=32;s>0;s>>=1) p += __shfl_xor(p, s);
    if (lane==0) slog[wid][e] = f16q(p);
  }
  if (lane==0){
    float mx=-1e30f;
    for (int e=0;e<NE_;e++) mx = fmaxf(mx, slog[wid][e]);
    float pr[NE_]; float sum=0.f;
    for (int e=0;e<NE_;e++){ float v=__expf(slog[wid][e]-mx); pr[e]=v; sum+=v; }
    for (int e=0;e<NE_;e++) pr[e] = pr[e]/sum;
    int   idx[TOPK_]; float val[TOPK_]; bool used[NE_];
    for (int e=0;e<NE_;e++) used[e]=false;
    float vs=0.f;
    for (int k=0;k<TOPK_;k++){
      float best=-1.f; int bi=0;
      for (int e=0;e<NE_;e++) if(!used[e] && pr[e]>best){best=pr[e];bi=e;}
      used[bi]=true; idx[k]=bi; val[k]=best; vs+=best;
    }
    float* rwr  = rw  + (size_t)n*NE_;
    float* rwfr = rwf + (size_t)n*NE_;
    for (int k=0;k<TOPK_;k++){
      float vraw = val[k]/vs;
      float q = f16q(vraw);
      rwr[idx[k]]  = q;
      rwfr[idx[k]] = vraw;
      if (q!=0.f) atomicAdd(counts+idx[k], 1);
    }
  }
}

// per-expert token lists, 4 blocks per expert (order-free, device atomics) ---
__global__ __launch_bounds__(256) void k_lists(const float* __restrict__ rw,
                                               const float* __restrict__ rwf,
                                               const int* __restrict__ counts,
                                               int* __restrict__ cdcs,
                                               int* __restrict__ tok_all,
                                               int* __restrict__ cnt_all)
{
  const int z = blockIdx.x, q = blockIdx.y;
  const int tid = threadIdx.x;
  const int e = rank_kth(counts, z);      // cheap; every block recomputes
  if (q==0 && tid==0) cdcs[z] = e;
  const int i = q*256 + tid;              // this thread's token
  bool take;
  if (z<8){
    take = (rw[(size_t)i*NE_+e] != 0.f);
  } else {
    const float vi = rwf[(size_t)i*NE_+e];
    int r=0;
    for (int m=0;m<BS_;m++){
      float vm = rwf[(size_t)m*NE_+e];
      r += (vm>vi) || (vm==vi && m<i);
    }
    take = (r<MAXNNZ_) && (rw[(size_t)i*NE_+e]!=0.f);
  }
  if (take){
    int slot = atomicAdd(&cnt_all[z], 1);
    tok_all[z*BS_+slot] = i;
  }
}

// --- fused up+gate gathered GEMM: 256 rows x 32 cols x {u,g}, 4 waves -------
// r20/r23 k-loop: swizzled dbuf LDS; depth-2 A (L2) + depth-4 B (HBM).
#define FSTEP(P, KT)                                                        \
{                                                                           \
  u16* A = ldsA[(P)&1]; u16* B = ldsB[(P)&1];                               \
  _Pragma("unroll")                                                         \
  for (int r=0;r<4;r++) *(h8*)&A[ldsx(ar + r*64, ach)] = Aset[(P)&1][r];    \
  *(h8*)&B[ldsx(br, ach)] = cvt8(Bsa[(P)], Bsb[(P)]);                       \
  if ((KT)+2 < NKF){                                                        \
    const int k2 = ((KT)+2)*32;                                             \
    _Pragma("unroll")                                                       \
    for (int r=0;r<4;r++) Aset[(P)&1][r] = *(const h8*)(ap[r]+k2);          \
  }                                                                         \
  if ((KT)+4 < NKF){                                                        \
    const int k4 = ((KT)+4)*32;                                             \
    Bsa[(P)] = *(const fv4*)(bp+k4); Bsb[(P)] = *(const fv4*)(bp+k4+4);     \
  }                                                                         \
  barrier_lgkm();                                                           \
  h8 af[4], fu[2], fg[2];                                                   \
  _Pragma("unroll")                                                         \
  for (int m=0;m<4;m++) af[m] = *(const h8*)&A[ldsx(w*64+m*16+lr, kq)];     \
  _Pragma("unroll")                                                         \
  for (int n2=0;n2<2;n2++){                                                 \
    fu[n2] = *(const h8*)&B[ldsx(   n2*16+lr, kq)];                         \
    fg[n2] = *(const h8*)&B[ldsx(32+n2*16+lr, kq)];                         \
  }                                                                         \
  _Pragma("unroll")                                                         \
  for (int m=0;m<4;m++)                                                     \
    _Pragma("unroll")                                                       \
    for (int n2=0;n2<2;n2++){                                               \
      au[m][n2]=__builtin_amdgcn_mfma_f32_16x16x32_f16(af[m],fu[n2],au[m][n2],0,0,0); \
      ag[m][n2]=__builtin_amdgcn_mfma_f32_16x16x32_f16(af[m],fg[n2],ag[m][n2],0,0,0); \
    }                                                                       \
}

__global__ __launch_bounds__(256, 2) void k_fused(const u16* __restrict__ xh,
                                               const float* __restrict__ uw,
                                               const float* __restrict__ gww,
                                               const float* __restrict__ ub,
                                               const float* __restrict__ gb,
                                               const float* __restrict__ rw,
                                               const int* __restrict__ cdcs,
                                               const int* __restrict__ tok_all,
                                               const int* __restrict__ cnt_all,
                                               u16* __restrict__ act)
{
  const int z=blockIdx.z, bx=blockIdx.x, by=blockIdx.y;
  const int cnt = cnt_all[z];
  if (by*256 >= cnt) return;
  const int e = cdcs[z];
  __shared__ __align__(16) u16 ldsA[2][256*32];
  __shared__ __align__(16) u16 ldsB[2][64*32];   // rows 0-31 U, 32-63 G
  const int tid=threadIdx.x, lane=tid&63, w=tid>>6;
  const int lr = lane&15, kq = lane>>4;
  const int ar = tid>>2, ach = tid&3;
  const u16* ap[4];
  #pragma unroll
  for (int r=0;r<4;r++){
    const int tok = tok_all[z*BS_ + by*256 + ar + r*64];
    ap[r] = xh + (size_t)tok*HID + ach*8;
  }
  const int br = ar;
  const float* bp = (br<32 ? uw  + ((size_t)e*EW_ + bx*32 + br)*HID
                           : gww + ((size_t)e*EW_ + bx*32 + (br-32))*HID) + ach*8;

  f32x4 au[4][2], ag[4][2];
  #pragma unroll
  for (int i=0;i<4;i++)
    #pragma unroll
    for (int j=0;j<2;j++)
      #pragma unroll
      for (int q=0;q<4;q++){ au[i][j][q]=0.f; ag[i][j][q]=0.f; }

  h8 Aset[2][4]; fv4 Bsa[4], Bsb[4];
  #pragma unroll
  for (int r=0;r<4;r++){
    Aset[0][r] = *(const h8*)ap[r];
    Aset[1][r] = *(const h8*)(ap[r]+32);
  }
  #pragma unroll
  for (int p=0;p<4;p++){
    Bsa[p] = *(const fv4*)(bp+p*32); Bsb[p] = *(const fv4*)(bp+p*32+4);
  }

  const int NKF = HID/32;  // 64
  for (int kt=0; kt<NKF; kt+=4){
    FSTEP(0, kt)
    FSTEP(1, kt+1)
    FSTEP(2, kt+2)
    FSTEP(3, kt+3)
  }

  #pragma unroll
  for (int n2=0;n2<2;n2++){
    const int col = bx*32 + n2*16 + lr;
    const float ubv = ub[(size_t)e*EW_ + col];
    const float gbv = gb[(size_t)e*EW_ + col];
    #pragma unroll
    for (int m=0;m<4;m++){
      #pragma unroll
      for (int j=0;j<4;j++){
        const int s = by*256 + w*64 + m*16 + kq*4 + j;
        if (s < cnt){
          float upv = f16q(au[m][n2][j] + ubv);
          float gtv = f16q(ag[m][n2][j] + gbv);
          float wv = rw[(size_t)tok_all[z*BS_+s]*NE_ + e];
          float gc = fminf(gtv, 7.0f);
          float uc = fminf(fmaxf(upv,-7.0f),7.0f);
          float glu = gc * (1.f/(1.f+__expf(-gc*1.702f)));
          act[((size_t)z*BS_+s)*ORIG_ + col] = f2h_bits((uc+1.f)*glu*wv);
        }
      }
    }
  }
}

// --- gathered down GEMM: 256 rows x 64 cols, FULL K=2880; direct f32 -------
// scatter-add into d_out (contrib/combine eliminated).
#define DSTEP(P, KT)                                                        \
{                                                                           \
  u16* A = ldsA[(P)&1]; u16* B = ldsB[(P)&1];                               \
  _Pragma("unroll")                                                         \
  for (int r=0;r<4;r++) *(h8*)&A[ldsx(ar + r*64, ach)] = Aset[(P)&1][r];    \
  *(h8*)&B[ldsx(br, ach)] = cvt8(Bsa[(P)], Bsb[(P)]);                       \
  if ((KT)+2 < NKD){                                                        \
    const int k2 = ((KT)+2)*32;                                             \
    _Pragma("unroll")                                                       \
    for (int r=0;r<4;r++) Aset[(P)&1][r] = *(const h8*)(ap[r]+k2);          \
  }                                                                         \
  if ((KT)+4 < NKD){                                                        \
    const int k4 = ((KT)+4)*32;                                             \
    Bsa[(P)] = *(const fv4*)(bp+k4); Bsb[(P)] = *(const fv4*)(bp+k4+4);     \
  }                                                                         \
  barrier_lgkm();                                                           \
  h8 af[4], bfr[4];                                                         \
  _Pragma("unroll")                                                         \
  for (int m=0;m<4;m++)    af[m]  = *(const h8*)&A[ldsx(w*64+m*16+lr, kq)]; \
  _Pragma("unroll")                                                         \
  for (int n2=0;n2<4;n2++) bfr[n2] = *(const h8*)&B[ldsx(n2*16+lr, kq)];    \
  _Pragma("unroll")                                                         \
  for (int m=0;m<4;m++)                                                     \
    _Pragma("unroll")                                                       \
    for (int n2=0;n2<4;n2++)                                                \
      acc[m][n2]=__builtin_amdgcn_mfma_f32_16x16x32_f16(af[m],bfr[n2],acc[m][n2],0,0,0); \
}

__global__ __launch_bounds__(256, 2) void k_down(const u16* __restrict__ act,
                                              const float* __restrict__ dw,
                                              const int* __restrict__ cdcs,
                                              const int* __restrict__ tok_all,
                                              const int* __restrict__ cnt_all,
                                              float* __restrict__ outf)
{
  const int z=blockIdx.z, bx=blockIdx.x, by=blockIdx.y;
  const int cnt = cnt_all[z];
  if (by*256 >= cnt) return;
  const int e = cdcs[z];
  __shared__ __align__(16) u16 ldsA[2][256*32];
  __shared__ __align__(16) u16 ldsB[2][64*32];
  const int tid=threadIdx.x, lane=tid&63, w=tid>>6;
  const int lr = lane&15, kq = lane>>4;
  const int ar = tid>>2, ach = tid&3;

  const u16* ap[4];
  #pragma unroll
  for (int r=0;r<4;r++)
    ap[r] = act + ((size_t)z*BS_ + by*256 + ar + r*64)*ORIG_ + ach*8;
  const int br = ar;
  const float* bp = dw + (size_t)(bx*64 + br)*NEWTOT + (size_t)e*EW_ + ach*8;

  f32x4 acc[4][4];
  #pragma unroll
  for (int i=0;i<4;i++)
    #pragma unroll
    for (int j=0;j<4;j++)
      #pragma unroll
      for (int q=0;q<4;q++) acc[i][j][q]=0.f;

  h8 Aset[2][4]; fv4 Bsa[4], Bsb[4];
  #pragma unroll
  for (int r=0;r<4;r++){
    Aset[0][r] = *(const h8*)ap[r];
    Aset[1][r] = *(const h8*)(ap[r]+32);
  }
  #pragma unroll
  for (int p=0;p<4;p++){
    Bsa[p] = *(const fv4*)(bp+p*32); Bsb[p] = *(const fv4*)(bp+p*32+4);
  }

  const int NKD = ORIG_/32;  // 90 = 22*4 + 2
  for (int kt=0; kt<88; kt+=4){
    DSTEP(0, kt)
    DSTEP(1, kt+1)
    DSTEP(2, kt+2)
    DSTEP(3, kt+3)
  }
  DSTEP(0, 88)
  DSTEP(1, 89)

  #pragma unroll
  for (int m=0;m<4;m++){
    #pragma unroll
    for (int j=0;j<4;j++){
      const int slot = by*256 + w*64 + m*16 + kq*4 + j;
      if (slot < cnt){
        const int tok = tok_all[z*BS_ + slot];
        #pragma unroll
        for (int n2=0;n2<4;n2++){
          const int col = bx*64 + n2*16 + lr;
          atomicAdd(outf + (size_t)tok*HID + col, f16q(acc[m][n2][j]));
        }
      }
    }
  }
}

extern "C" void kernel_launch(void* const* d_in, const int* in_sizes, int n_in,
                              void* d_out, int out_size, void* d_ws, size_t ws_size,
                              hipStream_t stream)
{
  const float* x  = (const float*)d_in[0];
  const float* gw = (const float*)d_in[1];
  const float* u  = (const float*)d_in[2];
  const float* g  = (const float*)d_in[3];
  const float* dw = (const float*)d_in[4];
  const float* ub = (const float*)d_in[5];
  const float* gb = (const float*)d_in[6];

  char* ws = (char*)d_ws;
  size_t off = 0;
  auto alloc = [&](size_t bytes)->void*{ void* p = ws + off; off += (bytes + 255) & ~(size_t)255; return p; };
  float* rw     = (float*)alloc((size_t)BS_*NE_*4);
  float* rwf    = (float*)alloc((size_t)BS_*NE_*4);
  int*   counts = (int*)  alloc(NE_*4);
  int*   cnt_all= (int*)  alloc(16*4);
  int*   tok_all= (int*)  alloc((size_t)16*BS_*4);
  size_t zero_span = off;   // rw+rwf+counts+cnt_all+tok_all zeroed
  int*   cdcs   = (int*)  alloc(16*4);
  u16*   xh     = (u16*)  alloc((size_t)BS_*HID*2);
  u16*   act    = (u16*)  alloc((size_t)16*BS_*ORIG_*2);
  if (off > ws_size) return;

  hipMemsetAsync(ws, 0, zero_span, stream);
  hipMemsetAsync(d_out, 0, (size_t)BS_*HID*4, stream);   // f32 output accumulator

  k_gate <<<BS_/4, 256, 0, stream>>>(x, gw, rw, rwf, counts, xh);
  k_lists<<<dim3(16,4), 256, 0, stream>>>(rw, rwf, counts, cdcs, tok_all, cnt_all);

  k_fused<<<dim3(ORIG_/32, 4, 16), 256, 0, stream>>>(xh, u, g, ub, gb, rw,
                                                     cdcs, tok_all, cnt_all, act);
  k_down <<<dim3(HID/64, 4, 16), 256, 0, stream>>>(act, dw, cdcs, tok_all,
                                                   cnt_all, (float*)d_out);
}

// Round 27
// 534.101 us; speedup vs baseline: 1.0137x; 1.0137x over previous
//
#include <hip/hip_runtime.h>

#define HID 2048
#define NE_ 32
#define EW_ 2944
#define ORIG_ 2880
#define TOPK_ 4
#define MAXNNZ_ 256
#define BS_ 1024
#define NEWTOT (NE_*EW_)

typedef unsigned short u16;
typedef _Float16 h8  __attribute__((ext_vector_type(8)));
typedef float  f32x4 __attribute__((ext_vector_type(4)));
typedef float  fv4   __attribute__((ext_vector_type(4)));

__device__ __forceinline__ u16 f2h_bits(float f){
  union{ _Float16 h; u16 u; } c; c.h = (_Float16)f; return c.u;
}
__device__ __forceinline__ float f16q(float f){ return (float)(_Float16)f; }

__device__ __forceinline__ h8 cvt8(fv4 a, fv4 b){
  h8 r;
  r[0]=(_Float16)a[0]; r[1]=(_Float16)a[1]; r[2]=(_Float16)a[2]; r[3]=(_Float16)a[3];
  r[4]=(_Float16)b[0]; r[5]=(_Float16)b[1]; r[6]=(_Float16)b[2]; r[7]=(_Float16)b[3];
  return r;
}
// XOR-swizzled LDS index (halfword units), 64B rows, 16B chunks; write and
// read use the same per-row bijection.
__device__ __forceinline__ int ldsx(int row, int chunk){
  return row*32 + ((chunk ^ ((row>>1)&3))*8);
}

// LDS-visibility-only barrier: global loads into registers stay in flight.
__device__ __forceinline__ void barrier_lgkm(){
  asm volatile("s_waitcnt lgkmcnt(0)" ::: "memory");
  __builtin_amdgcn_s_barrier();
  __builtin_amdgcn_sched_barrier(0);
}

// expert ranking by count desc, tie -> lower index; returns k-th expert
__device__ __forceinline__ int rank_kth(const int* counts, int kth){
  int cnt[NE_]; bool used[NE_];
  for (int e=0;e<NE_;e++){ cnt[e]=counts[e]; used[e]=false; }
  int bi=0;
  for (int k=0;k<=kth;k++){
    int best=-1; bi=0;
    for (int e=0;e<NE_;e++) if(!used[e] && cnt[e]>best){best=cnt[e];bi=e;}
    used[bi]=true;
  }
  return bi;
}

// ------- gating (f32 in, f16-quantized logits, top4) + xh emission ----------
__global__ __launch_bounds__(256) void k_gate(const float* __restrict__ x,
                                              const float* __restrict__ gw,
                                              float* __restrict__ rw,
                                              float* __restrict__ rwf,
                                              int* __restrict__ counts,
                                              u16* __restrict__ xh)
{
  __shared__ float slog[4][NE_];
  const int tid = threadIdx.x, wid = tid>>6, lane = tid&63;
  const int n = blockIdx.x*4 + wid;
  const float* xr = x + (size_t)n*HID + lane*32;
  float xf[32];
  #pragma unroll
  for (int i=0;i<8;i++){
    fv4 v = *(const fv4*)(xr + i*4);
    #pragma unroll
    for (int j=0;j<4;j++) xf[i*4+j] = v[j];
  }
  #pragma unroll
  for (int c=0;c<4;c++){
    h8 hv;
    #pragma unroll
    for (int j=0;j<8;j++) hv[j] = (_Float16)xf[c*8+j];
    *(h8*)(xh + (size_t)n*HID + lane*32 + c*8) = hv;
  }
  for (int e=0;e<NE_;e++){
    const float* gr = gw + (size_t)e*HID + lane*32;
    float p = 0.f;
    #pragma unroll
    for (int i=0;i<8;i++){
      fv4 v = *(const fv4*)(gr + i*4);
      #pragma unroll
      for (int j=0;j<4;j++) p += xf[i*4+j]*v[j];
    }
    #pragma unroll
    for (int s=32;s>0;s>>=1) p += __shfl_xor(p, s);
    if (lane==0) slog[wid][e] = f16q(p);
  }
  if (lane==0){
    float mx=-1e30f;
    for (int e=0;e<NE_;e++) mx = fmaxf(mx, slog[wid][e]);
    float pr[NE_]; float sum=0.f;
    for (int e=0;e<NE_;e++){ float v=__expf(slog[wid][e]-mx); pr[e]=v; sum+=v; }
    for (int e=0;e<NE_;e++) pr[e] = pr[e]/sum;
    int   idx[TOPK_]; float val[TOPK_]; bool used[NE_];
    for (int e=0;e<NE_;e++) used[e]=false;
    float vs=0.f;
    for (int k=0;k<TOPK_;k++){
      float best=-1.f; int bi=0;
      for (int e=0;e<NE_;e++) if(!used[e] && pr[e]>best){best=pr[e];bi=e;}
      used[bi]=true; idx[k]=bi; val[k]=best; vs+=best;
    }
    float* rwr  = rw  + (size_t)n*NE_;
    float* rwfr = rwf + (size_t)n*NE_;
    for (int k=0;k<TOPK_;k++){
      float vraw = val[k]/vs;
      float q = f16q(vraw);
      rwr[idx[k]]  = q;
      rwfr[idx[k]] = vraw;
      if (q!=0.f) atomicAdd(counts+idx[k], 1);
    }
  }
}

// per-expert token lists, 4 blocks per expert (order-free, device atomics) ---
__global__ __launch_bounds__(256) void k_lists(const float* __restrict__ rw,
                                               const float* __restrict__ rwf,
                                               const int* __restrict__ counts,
                                               int* __restrict__ cdcs,
                                               int* __restrict__ tok_all,
                                               int* __restrict__ cnt_all,
                                               int* __restrict__ inv,
                                               int* __restrict__ invcnt)
{
  const int z = blockIdx.x, q = blockIdx.y;
  const int tid = threadIdx.x;
  const int e = rank_kth(counts, z);      // cheap; every block recomputes
  if (q==0 && tid==0) cdcs[z] = e;
  const int i = q*256 + tid;              // this thread's token
  bool take;
  if (z<8){
    take = (rw[(size_t)i*NE_+e] != 0.f);
  } else {
    const float vi = rwf[(size_t)i*NE_+e];
    int r=0;
    for (int m=0;m<BS_;m++){
      float vm = rwf[(size_t)m*NE_+e];
      r += (vm>vi) || (vm==vi && m<i);
    }
    take = (r<MAXNNZ_) && (rw[(size_t)i*NE_+e]!=0.f);
  }
  if (take){
    int slot = atomicAdd(&cnt_all[z], 1);
    tok_all[z*BS_+slot] = i;
    int c = atomicAdd(&invcnt[i], 1);
    inv[i*4+c] = (z<<16) | slot;
  }
}

// --- fused up+gate gathered GEMM: 256 rows x 32 cols x {u,g}, 4 waves -------
// r20/r23 k-loop: swizzled dbuf LDS; depth-2 A (L2) + depth-4 B (HBM).
#define FSTEP(P, KT)                                                        \
{                                                                           \
  u16* A = ldsA[(P)&1]; u16* B = ldsB[(P)&1];                               \
  _Pragma("unroll")                                                         \
  for (int r=0;r<4;r++) *(h8*)&A[ldsx(ar + r*64, ach)] = Aset[(P)&1][r];    \
  *(h8*)&B[ldsx(br, ach)] = cvt8(Bsa[(P)], Bsb[(P)]);                       \
  if ((KT)+2 < NKF){                                                        \
    const int k2 = ((KT)+2)*32;                                             \
    _Pragma("unroll")                                                       \
    for (int r=0;r<4;r++) Aset[(P)&1][r] = *(const h8*)(ap[r]+k2);          \
  }                                                                         \
  if ((KT)+4 < NKF){                                                        \
    const int k4 = ((KT)+4)*32;                                             \
    Bsa[(P)] = *(const fv4*)(bp+k4); Bsb[(P)] = *(const fv4*)(bp+k4+4);     \
  }                                                                         \
  barrier_lgkm();                                                           \
  h8 af[4], fu[2], fg[2];                                                   \
  _Pragma("unroll")                                                         \
  for (int m=0;m<4;m++) af[m] = *(const h8*)&A[ldsx(w*64+m*16+lr, kq)];     \
  _Pragma("unroll")                                                         \
  for (int n2=0;n2<2;n2++){                                                 \
    fu[n2] = *(const h8*)&B[ldsx(   n2*16+lr, kq)];                         \
    fg[n2] = *(const h8*)&B[ldsx(32+n2*16+lr, kq)];                         \
  }                                                                         \
  _Pragma("unroll")                                                         \
  for (int m=0;m<4;m++)                                                     \
    _Pragma("unroll")                                                       \
    for (int n2=0;n2<2;n2++){                                               \
      au[m][n2]=__builtin_amdgcn_mfma_f32_16x16x32_f16(af[m],fu[n2],au[m][n2],0,0,0); \
      ag[m][n2]=__builtin_amdgcn_mfma_f32_16x16x32_f16(af[m],fg[n2],ag[m][n2],0,0,0); \
    }                                                                       \
}

__global__ __launch_bounds__(256, 2) void k_fused(const u16* __restrict__ xh,
                                               const float* __restrict__ uw,
                                               const float* __restrict__ gww,
                                               const float* __restrict__ ub,
                                               const float* __restrict__ gb,
                                               const float* __restrict__ rw,
                                               const int* __restrict__ cdcs,
                                               const int* __restrict__ tok_all,
                                               const int* __restrict__ cnt_all,
                                               u16* __restrict__ act)
{
  const int z=blockIdx.z, bx=blockIdx.x, by=blockIdx.y;
  const int cnt = cnt_all[z];
  if (by*256 >= cnt) return;
  const int e = cdcs[z];
  __shared__ __align__(16) u16 ldsA[2][256*32];
  __shared__ __align__(16) u16 ldsB[2][64*32];   // rows 0-31 U, 32-63 G
  const int tid=threadIdx.x, lane=tid&63, w=tid>>6;
  const int lr = lane&15, kq = lane>>4;
  const int ar = tid>>2, ach = tid&3;
  const u16* ap[4];
  #pragma unroll
  for (int r=0;r<4;r++){
    const int tok = tok_all[z*BS_ + by*256 + ar + r*64];
    ap[r] = xh + (size_t)tok*HID + ach*8;
  }
  const int br = ar;
  const float* bp = (br<32 ? uw  + ((size_t)e*EW_ + bx*32 + br)*HID
                           : gww + ((size_t)e*EW_ + bx*32 + (br-32))*HID) + ach*8;

  f32x4 au[4][2], ag[4][2];
  #pragma unroll
  for (int i=0;i<4;i++)
    #pragma unroll
    for (int j=0;j<2;j++)
      #pragma unroll
      for (int q=0;q<4;q++){ au[i][j][q]=0.f; ag[i][j][q]=0.f; }

  h8 Aset[2][4]; fv4 Bsa[4], Bsb[4];
  #pragma unroll
  for (int r=0;r<4;r++){
    Aset[0][r] = *(const h8*)ap[r];
    Aset[1][r] = *(const h8*)(ap[r]+32);
  }
  #pragma unroll
  for (int p=0;p<4;p++){
    Bsa[p] = *(const fv4*)(bp+p*32); Bsb[p] = *(const fv4*)(bp+p*32+4);
  }

  const int NKF = HID/32;  // 64
  for (int kt=0; kt<NKF; kt+=4){
    FSTEP(0, kt)
    FSTEP(1, kt+1)
    FSTEP(2, kt+2)
    FSTEP(3, kt+3)
  }

  #pragma unroll
  for (int n2=0;n2<2;n2++){
    const int col = bx*32 + n2*16 + lr;
    const float ubv = ub[(size_t)e*EW_ + col];
    const float gbv = gb[(size_t)e*EW_ + col];
    #pragma unroll
    for (int m=0;m<4;m++){
      #pragma unroll
      for (int j=0;j<4;j++){
        const int s = by*256 + w*64 + m*16 + kq*4 + j;
        if (s < cnt){
          float upv = f16q(au[m][n2][j] + ubv);
          float gtv = f16q(ag[m][n2][j] + gbv);
          float wv = rw[(size_t)tok_all[z*BS_+s]*NE_ + e];
          float gc = fminf(gtv, 7.0f);
          float uc = fminf(fmaxf(upv,-7.0f),7.0f);
          float glu = gc * (1.f/(1.f+__expf(-gc*1.702f)));
          act[((size_t)z*BS_+s)*ORIG_ + col] = f2h_bits((uc+1.f)*glu*wv);
        }
      }
    }
  }
}

// --- gathered down GEMM: 256 rows x 64 cols, FULL K=2880 (no split) ---------
#define DSTEP(P, KT)                                                        \
{                                                                           \
  u16* A = ldsA[(P)&1]; u16* B = ldsB[(P)&1];                               \
  _Pragma("unroll")                                                         \
  for (int r=0;r<4;r++) *(h8*)&A[ldsx(ar + r*64, ach)] = Aset[(P)&1][r];    \
  *(h8*)&B[ldsx(br, ach)] = cvt8(Bsa[(P)], Bsb[(P)]);                       \
  if ((KT)+2 < NKD){                                                        \
    const int k2 = ((KT)+2)*32;                                             \
    _Pragma("unroll")                                                       \
    for (int r=0;r<4;r++) Aset[(P)&1][r] = *(const h8*)(ap[r]+k2);          \
  }                                                                         \
  if ((KT)+4 < NKD){                                                        \
    const int k4 = ((KT)+4)*32;                                             \
    Bsa[(P)] = *(const fv4*)(bp+k4); Bsb[(P)] = *(const fv4*)(bp+k4+4);     \
  }                                                                         \
  barrier_lgkm();                                                           \
  h8 af[4], bfr[4];                                                         \
  _Pragma("unroll")                                                         \
  for (int m=0;m<4;m++)    af[m]  = *(const h8*)&A[ldsx(w*64+m*16+lr, kq)]; \
  _Pragma("unroll")                                                         \
  for (int n2=0;n2<4;n2++) bfr[n2] = *(const h8*)&B[ldsx(n2*16+lr, kq)];    \
  _Pragma("unroll")                                                         \
  for (int m=0;m<4;m++)                                                     \
    _Pragma("unroll")                                                       \
    for (int n2=0;n2<4;n2++)                                                \
      acc[m][n2]=__builtin_amdgcn_mfma_f32_16x16x32_f16(af[m],bfr[n2],acc[m][n2],0,0,0); \
}

__global__ __launch_bounds__(256, 2) void k_down(const u16* __restrict__ act,
                                              const float* __restrict__ dw,
                                              const int* __restrict__ cdcs,
                                              const int* __restrict__ cnt_all,
                                              u16* __restrict__ contrib)
{
  const int z=blockIdx.z, bx=blockIdx.x, by=blockIdx.y;
  const int cnt = cnt_all[z];
  if (by*256 >= cnt) return;
  const int e = cdcs[z];
  __shared__ __align__(16) u16 ldsA[2][256*32];
  __shared__ __align__(16) u16 ldsB[2][64*32];
  const int tid=threadIdx.x, lane=tid&63, w=tid>>6;
  const int lr = lane&15, kq = lane>>4;
  const int ar = tid>>2, ach = tid&3;

  const u16* ap[4];
  #pragma unroll
  for (int r=0;r<4;r++)
    ap[r] = act + ((size_t)z*BS_ + by*256 + ar + r*64)*ORIG_ + ach*8;
  const int br = ar;
  const float* bp = dw + (size_t)(bx*64 + br)*NEWTOT + (size_t)e*EW_ + ach*8;

  f32x4 acc[4][4];
  #pragma unroll
  for (int i=0;i<4;i++)
    #pragma unroll
    for (int j=0;j<4;j++)
      #pragma unroll
      for (int q=0;q<4;q++) acc[i][j][q]=0.f;

  h8 Aset[2][4]; fv4 Bsa[4], Bsb[4];
  #pragma unroll
  for (int r=0;r<4;r++){
    Aset[0][r] = *(const h8*)ap[r];
    Aset[1][r] = *(const h8*)(ap[r]+32);
  }
  #pragma unroll
  for (int p=0;p<4;p++){
    Bsa[p] = *(const fv4*)(bp+p*32); Bsb[p] = *(const fv4*)(bp+p*32+4);
  }

  const int NKD = ORIG_/32;  // 90 = 22*4 + 2
  for (int kt=0; kt<88; kt+=4){
    DSTEP(0, kt)
    DSTEP(1, kt+1)
    DSTEP(2, kt+2)
    DSTEP(3, kt+3)
  }
  DSTEP(0, 88)
  DSTEP(1, 89)

  #pragma unroll
  for (int m=0;m<4;m++){
    #pragma unroll
    for (int j=0;j<4;j++){
      const int slot = by*256 + w*64 + m*16 + kq*4 + j;
      if (slot < cnt){
        #pragma unroll
        for (int n2=0;n2<4;n2++){
          const int col = bx*64 + n2*16 + lr;
          contrib[((size_t)z*BS_ + slot)*HID + col] = f2h_bits(acc[m][n2][j]);
        }
      }
    }
  }
}

// ---- combine: out[n][h] = sum over token n's <=4 lists (single plane) ------
__global__ __launch_bounds__(256) void k_combine(const u16* __restrict__ contrib,
                                                 const int* __restrict__ inv,
                                                 const int* __restrict__ invcnt,
                                                 float* __restrict__ out)
{
  const int gid = blockIdx.x*256 + threadIdx.x;
  const int base = gid*8;
  const int n = base >> 11;
  const int h = base & 2047;
  float acc[8];
  #pragma unroll
  for (int q=0;q<8;q++) acc[q]=0.f;
  const int c = invcnt[n];
  for (int j=0;j<c;j++){
    const int code = inv[n*4+j];
    const int z = code>>16;
    const int slot = code & 0xFFFF;
    const u16* p = contrib + ((size_t)z*BS_ + slot)*HID + h;
    h8 v0 = *(const h8*)p;
    #pragma unroll
    for (int q=0;q<8;q++) acc[q] += (float)v0[q];
  }
  fv4 o0, o1;
  #pragma unroll
  for (int q=0;q<4;q++){ o0[q]=acc[q]; o1[q]=acc[4+q]; }
  *(fv4*)(out + base) = o0;
  *(fv4*)(out + base + 4) = o1;
}

extern "C" void kernel_launch(void* const* d_in, const int* in_sizes, int n_in,
                              void* d_out, int out_size, void* d_ws, size_t ws_size,
                              hipStream_t stream)
{
  const float* x  = (const float*)d_in[0];
  const float* gw = (const float*)d_in[1];
  const float* u  = (const float*)d_in[2];
  const float* g  = (const float*)d_in[3];
  const float* dw = (const float*)d_in[4];
  const float* ub = (const float*)d_in[5];
  const float* gb = (const float*)d_in[6];

  char* ws = (char*)d_ws;
  size_t off = 0;
  auto alloc = [&](size_t bytes)->void*{ void* p = ws + off; off += (bytes + 255) & ~(size_t)255; return p; };
  float* rw     = (float*)alloc((size_t)BS_*NE_*4);
  float* rwf    = (float*)alloc((size_t)BS_*NE_*4);
  int*   counts = (int*)  alloc(NE_*4);
  int*   invcnt = (int*)  alloc(BS_*4);
  int*   cnt_all= (int*)  alloc(16*4);
  int*   tok_all= (int*)  alloc((size_t)16*BS_*4);
  size_t zero_span = off;   // rw+rwf+counts+invcnt+cnt_all+tok_all zeroed
  int*   cdcs   = (int*)  alloc(16*4);
  int*   inv    = (int*)  alloc((size_t)BS_*4*4);
  u16*   xh     = (u16*)  alloc((size_t)BS_*HID*2);
  u16*   act    = (u16*)  alloc((size_t)16*BS_*ORIG_*2);
  u16*   contrib= (u16*)  alloc((size_t)16*BS_*HID*2);
  if (off > ws_size) return;

  hipMemsetAsync(ws, 0, zero_span, stream);

  k_gate <<<BS_/4, 256, 0, stream>>>(x, gw, rw, rwf, counts, xh);
  k_lists<<<dim3(16,4), 256, 0, stream>>>(rw, rwf, counts, cdcs, tok_all,
                                          cnt_all, inv, invcnt);

  k_fused<<<dim3(ORIG_/32, 4, 16), 256, 0, stream>>>(xh, u, g, ub, gb, rw,
                                                     cdcs, tok_all, cnt_all, act);
  k_down <<<dim3(HID/64, 4, 16), 256, 0, stream>>>(act, dw, cdcs, cnt_all, contrib);
  k_combine<<<BS_*HID/(256*8), 256, 0, stream>>>(contrib, inv, invcnt, (float*)d_out);
}